// Round 3
// baseline (834.586 us; speedup 1.0000x reference)
//
#include <hip/hip_runtime.h>
#include <hip/hip_bf16.h>

#define NA 4096
#define NP 49152

// ---------------- ws layout (float-element offsets) ----------------
constexpr int WS_Y     = 0;                 // 512*25 quadrature sph
constexpr int WS_G     = 12800;             // 5625 Gaunt tensor (i*9+j)*25+k
constexpr int WS_NATT  = WS_G + 5632;       // int: nnz of attention list
constexpr int WS_ATTW  = WS_NATT + 8;       // 1024 floats
constexpr int WS_ATTIJ = WS_ATTW + 1024;    // 1024 ints (i | j<<5 | k<<9), sorted by k
constexpr int WS_TDOFS = WS_ATTIJ + 1024;   // 16 ints (per-k offsets, 10 used)
constexpr int WS_TDW   = WS_TDOFS + 16;     // 512 floats
constexpr int WS_TDIJ  = WS_TDW + 512;      // 512 ints (i | j<<5 | li<<10 | lj<<12)
constexpr int WS_AOFS  = WS_TDIJ + 512;     // 32 ints (attention per-k offsets, 26 used)
constexpr int WS_SH    = WS_AOFS + 32;      // NP*9  sh_b
constexpr int WS_RB    = WS_SH + NP*9;      // NP*16 radial basis
constexpr int WS_S     = WS_RB + NP*16;     // NP    scores
constexpr int WS_E     = WS_S + NP;         // NP    exp(s-m)
constexpr int WS_M     = WS_E + NP;         // NA    segment max (uint-encoded)
constexpr int WS_DEN   = WS_M + NA;         // NA
constexpr int WS_CNT   = WS_DEN + NA;       // NA
constexpr int WS_SUMS  = WS_CNT + NA;       // NA*144
constexpr int WS_X     = WS_SUMS + NA*144;  // NA*400
constexpr int WS_XQ    = WS_X + NA*400;
constexpr int WS_XK    = WS_XQ + NA*400;
constexpr int WS_XV    = WS_XK + NA*400;
constexpr int WS_AGG   = WS_XV + NA*400;
constexpr int WS_END   = WS_AGG + NA*400;   // ~40.6 MB

// Gauss-Legendre 16-point nodes/weights (A&S table 25.4), ascending.
__device__ const float  GLX[16] = {
  -0.98940093499164993f, -0.94457502307323258f, -0.86563120238783174f, -0.75540440835500303f,
  -0.61787624440264375f, -0.45801677765722739f, -0.28160355077925891f, -0.09501250983763744f,
   0.09501250983763744f,  0.28160355077925891f,  0.45801677765722739f,  0.61787624440264375f,
   0.75540440835500303f,  0.86563120238783174f,  0.94457502307323258f,  0.98940093499164993f };
__device__ const double GLW[16] = {
  0.02715245941175409, 0.06225352393864789, 0.09515851168249278, 0.12462897125553387,
  0.14959598881657673, 0.16915651939500254, 0.18260341504492359, 0.18945061045506850,
  0.18945061045506850, 0.18260341504492359, 0.16915651939500254, 0.14959598881657673,
  0.12462897125553387, 0.09515851168249278, 0.06225352393864789, 0.02715245941175409 };

#define PI_D 3.14159265358979323846

// NaN/Inf scrub: insurance + failure localization.
__device__ __forceinline__ float scrub(float v){
  if(!(v == v)) return 0.f;
  return fminf(fmaxf(v, -1e30f), 1e30f);
}

// monotone float<->uint encoding for atomicMax on signed floats
__device__ __forceinline__ unsigned fenc(float f){
  int b = __float_as_int(f);
  return (b >= 0) ? ((unsigned)b | 0x80000000u) : (unsigned)(~b);
}
__device__ __forceinline__ float fdec(unsigned u){
  int b = (u & 0x80000000u) ? (int)(u & 0x7fffffffu) : (int)(~u);
  return __int_as_float(b);
}

// full real spherical harmonics, lmax=4 (reference recurrence, f32)
__device__ void real_sph25(float ct, float phi, float* Y){
  float st = sqrtf(fmaxf(0.f, 1.f - ct*ct));
  float P[5][5];
  P[0][0] = 1.f;
  #pragma unroll
  for(int m=1;m<=4;m++) P[m][m] = -(2.f*m - 1.f)*st*P[m-1][m-1];
  #pragma unroll
  for(int m=0;m<4;m++) P[m+1][m] = (2.f*m + 1.f)*ct*P[m][m];
  #pragma unroll
  for(int m=0;m<=4;m++){
    #pragma unroll
    for(int l=m+2;l<=4;l++)
      P[l][m] = ((2.f*l - 1.f)*ct*P[l-1][m] - (float)(l+m-1)*P[l-2][m]) / (float)(l-m);
  }
  const double fact[9] = {1,1,2,6,24,120,720,5040,40320};
  int idx = 0;
  #pragma unroll
  for(int l=0;l<=4;l++){
    #pragma unroll
    for(int m=-l;m<=l;m++){
      int ma = (m < 0) ? -m : m;
      float Nn = (float)sqrt((2*l+1)/(4.0*PI_D)*fact[l-ma]/fact[l+ma]);
      float cs = (ma & 1) ? -1.f : 1.f;
      float v;
      if(m == 0)      v = Nn * P[l][0];
      else if(m > 0)  v = 1.4142135623730951f * Nn * cs * cosf(ma*phi) * P[l][ma];
      else            v = 1.4142135623730951f * Nn * cs * sinf(ma*phi) * P[l][ma];
      Y[idx++] = v;
    }
  }
}

// ---------------- quadrature: Y at 512 grid points ----------------
__global__ void kq_Y(float* ws){
  int g = blockIdx.x*256 + threadIdx.x;
  if(g >= 512) return;
  float ct  = GLX[g >> 5];
  float phi = (float)((g & 31) * (2.0*PI_D/32.0));
  float Y[25];
  real_sph25(ct, phi, Y);
  #pragma unroll
  for(int i=0;i<25;i++) ws[WS_Y + g*25 + i] = Y[i];
}

// ---------------- G[i,j,k] = sum_g w_g Y_i Y_j Y_k ----------------
__global__ void kq_G(float* ws){
  int t = blockIdx.x*256 + threadIdx.x;
  if(t >= 5625) return;
  int k = t % 25, j = (t/25) % 9, i = t/225;
  const float* Y = ws + WS_Y;
  double acc = 0.0;
  for(int g=0; g<512; g++){
    double w = GLW[g >> 5] * (2.0*PI_D/32.0);
    acc += w * (double)Y[g*25+i] * (double)Y[g*25+j] * (double)Y[g*25+k];
  }
  if(fabs(acc) < 1e-6) acc = 0.0;
  ws[WS_G + (i*9+j)*25 + k] = (float)acc;
}

// ---------------- compact G into sparse lists (sorted by k) ----------------
__global__ void kq_lists(float* ws){
  __shared__ int cA[25], cT[9], oA[26], oT[10];
  int t = threadIdx.x;
  const float* G = ws + WS_G;
  if(t < 25){ int c=0; for(int i=0;i<25;i++) for(int j=0;j<9;j++) if(G[(i*9+j)*25+t] != 0.f) c++; cA[t]=c; }
  if(t < 9){  int c=0; for(int i=0;i<9;i++)  for(int j=0;j<9;j++) if(G[(i*9+j)*25+t] != 0.f) c++; cT[t]=c; }
  __syncthreads();
  if(t == 0){
    int s=0; for(int k=0;k<25;k++){ oA[k]=s; s+=cA[k]; } oA[25]=s;
    ((int*)ws)[WS_NATT] = s;
    s=0; for(int k=0;k<9;k++){ oT[k]=s; s+=cT[k]; } oT[9]=s;
  }
  __syncthreads();
  float* attw = ws + WS_ATTW; int* attij = (int*)ws + WS_ATTIJ;
  int* aofs = (int*)ws + WS_AOFS;
  if(t < 26) aofs[t] = oA[t] < 1024 ? oA[t] : 1024;
  if(t < 25){
    int pos = oA[t];
    for(int i=0;i<25;i++) for(int j=0;j<9;j++){
      float w = G[(i*9+j)*25+t];
      if(w != 0.f && pos < 1024){ attw[pos]=w; attij[pos] = i | (j<<5) | (t<<9); pos++; }
    }
  }
  float* tdw = ws + WS_TDW; int* tdij = (int*)ws + WS_TDIJ; int* tdofs = (int*)ws + WS_TDOFS;
  if(t < 9){
    int pos = oT[t];
    for(int i=0;i<9;i++) for(int j=0;j<9;j++){
      float w = G[(i*9+j)*25+t];
      if(w != 0.f && pos < 512){
        int li = (i==0)?0:(i<4)?1:2, lj = (j==0)?0:(j<4)?1:2;
        tdw[pos]=w; tdij[pos] = i | (j<<5) | (li<<10) | (lj<<12); pos++;
      }
    }
    tdofs[t] = oT[t];
    if(t == 0) tdofs[9] = oT[9];
  }
}

// ---------------- per-pair: sh_b (closed form l<=2) + radial basis ----------------
__global__ void k_pair(const float* disp, float* ws){
  int p = blockIdx.x*256 + threadIdx.x;
  if(p >= NP) return;
  float dx = disp[3*p], dy = disp[3*p+1], dz = disp[3*p+2];
  float r = sqrtf(dx*dx + dy*dy + dz*dz);
  float inv = 1.f / fmaxf(r, 1e-9f);
  float ux = dx*inv, uy = dy*inv, uz = dz*inv;
  float sh[9];
  sh[0] = 0.28209479177387814f;
  sh[1] = 0.4886025119029199f * uy;
  sh[2] = 0.4886025119029199f * uz;
  sh[3] = 0.4886025119029199f * ux;
  sh[4] = 1.0925484305920792f * ux*uy;
  sh[5] = 1.0925484305920792f * uy*uz;
  sh[6] = 0.31539156525252005f * (3.f*uz*uz - 1.f);
  sh[7] = 1.0925484305920792f * ux*uz;
  sh[8] = 0.5462742152960396f * (ux*ux - uy*uy);
  #pragma unroll
  for(int i=0;i<9;i++) ws[WS_SH + p*9 + i] = scrub(sh[i]);
  float mask = (r < 5.f) ? 1.f : 0.f;
  #pragma unroll
  for(int k=1;k<=16;k++){
    float x  = (float)k * r * 0.2f;
    float px = 3.14159265358979323846f * x;
    float s  = (px < 1e-6f) ? 1.f : (sinf(px)/px);
    ws[WS_RB + p*16 + (k-1)] = scrub(s * mask);
  }
}

// ---------------- per-layer init: segment max to enc(-1e30), den to 0 ----------
__global__ void k_initm(float* ws){
  int a = blockIdx.x*256 + threadIdx.x;
  if(a >= NA) return;
  ((unsigned*)ws)[WS_M + a] = fenc(-1e30f);
  ws[WS_DEN + a] = 0.f;
}

// ---------------- TD tensor-product phase (16 pairs x 16 lanes) ----------------
__global__ __launch_bounds__(256) void k_td(const int* aZ, const int* nbr,
    const float* Wrad, const float* W1, const float* W2,
    const float* W3, float* ws){
  __shared__ float sh_s[16][9];
  __shared__ float tp_s[16][9][16];
  int tid = threadIdx.x, pl = tid >> 4, g = tid & 15;
  int p = blockIdx.x*16 + pl;
  int dst = nbr[2*p], src = nbr[2*p+1];
  int Zj = aZ[src];
  if(g < 9) sh_s[pl][g] = ws[WS_SH + p*9 + g];
  float rbv = ws[WS_RB + p*16 + g];
  // y0[g] = sum_k rb[k] * W_rad[Zj,k,g]
  float y0 = 0.f;
  #pragma unroll
  for(int k=0;k<16;k++){
    float rk = __shfl(rbv, k, 16);
    y0 += rk * Wrad[(Zj*16+k)*16+g];
  }
  // rank-1 projections: A1[d,g], A2[d,g]
  float A1[3] = {0,0,0}, A2[3] = {0,0,0};
  #pragma unroll
  for(int fp=0;fp<16;fp++){
    float v = __shfl(y0, fp, 16);
    #pragma unroll
    for(int d=0;d<3;d++){
      A1[d] += v * W1[(d*16+fp)*16+g];
      A2[d] += v * W2[(d*16+fp)*16+g];
    }
  }
  __syncthreads();
  const float* tdw = ws + WS_TDW;
  const int* tdij  = (const int*)ws + WS_TDIJ;
  const int* tdofs = (const int*)ws + WS_TDOFS;
  #pragma unroll
  for(int k=0;k<9;k++){
    float acc = 0.f;
    int e1 = tdofs[k+1];
    for(int e=tdofs[k]; e<e1; e++){
      float w = tdw[e]; int meta = tdij[e];
      int i = meta & 31, j = (meta>>5) & 15, li = (meta>>10) & 3, lj = (meta>>12) & 3;
      float a1 = (li==0)?A1[0]:(li==1)?A1[1]:A1[2];
      float a2 = (lj==0)?A2[0]:(lj==1)?A2[1]:A2[2];
      acc += w * sh_s[pl][i] * sh_s[pl][j] * a1 * a2;
    }
    tp_s[pl][k][g] = acc;
  }
  __syncthreads();
  float* sums = ws + WS_SUMS;
  #pragma unroll
  for(int k=0;k<9;k++){
    int d = (k==0)?0:(k<4)?1:2;
    float acc = 0.f;
    #pragma unroll
    for(int f2=0;f2<16;f2++) acc += tp_s[pl][k][f2] * W3[(d*16+f2)*16+g];
    unsafeAtomicAdd(&sums[dst*144 + k*16 + g], scrub(acc));
  }
  if(g == 0) unsafeAtomicAdd(ws + WS_CNT + dst, 1.f);
}

// ---------------- mean + pad to 25 rows ----------------
__global__ void k_x(float* ws){
  int idx = blockIdx.x*256 + threadIdx.x;
  if(idx >= NA*400) return;
  int a = idx/400, r2 = idx%400, i = r2>>4, f = r2&15;
  float v = 0.f;
  if(i < 9){
    float c = ws[WS_CNT + a];
    v = ws[WS_SUMS + a*144 + i*16 + f] / fmaxf(c, 1.f);
  }
  ws[WS_X + idx] = scrub(v);
}

// ---------------- per-atom Q/K/V pdense (16 atoms x 16 lanes) ----------------
__global__ __launch_bounds__(256) void k_qkv(const float* Wq,
    const float* Wk, const float* Wv, float* ws){
  int tid = threadIdx.x, al = tid >> 4, g = tid & 15;
  int a = blockIdx.x*16 + al;
  const float* x = ws + WS_X + a*400;
  int i = 0;
  #pragma unroll
  for(int l=0;l<5;l++){
    float wq[16], wk[16], wv[16];
    #pragma unroll
    for(int f2=0;f2<16;f2++){
      wq[f2] = Wq[(l*16+f2)*16+g];
      wk[f2] = Wk[(l*16+f2)*16+g];
      wv[f2] = Wv[(l*16+f2)*16+g];
    }
    for(int mi=0; mi<2*l+1; mi++, i++){
      float q=0.f, k2=0.f, v2=0.f;
      #pragma unroll
      for(int f2=0;f2<16;f2++){
        float xv = x[i*16+f2];
        q += xv*wq[f2]; k2 += xv*wk[f2]; v2 += xv*wv[f2];
      }
      ws[WS_XQ + a*400 + i*16 + g] = q;
      ws[WS_XK + a*400 + i*16 + g] = k2;
      ws[WS_XV + a*400 + i*16 + g] = v2;
    }
  }
}

// Conflict-free M build: M[i,k] = sum_j G[i,j,k]*sh[j].
// Attention list is sorted by k with per-k offsets; lane g owns rows k=g,g+16
// (exclusive writes, no atomics). 8 pairs x 16 lanes per block.
#define M_BUILD() \
  do { \
    float4* M4 = (float4*)&Ml[0][0]; \
    for(int t0=tid; t0<8*25*7; t0+=128) M4[t0] = make_float4(0.f,0.f,0.f,0.f); \
    if(g < 9) sh_s[pl][g] = ws[WS_SH + p*9 + g]; \
    __syncthreads(); \
    const float* attw = ws + WS_ATTW; \
    const int* attij  = (const int*)ws + WS_ATTIJ; \
    const int* aofs   = (const int*)ws + WS_AOFS; \
    for(int kr=g; kr<25; kr+=16){ \
      float* Mrow = &Ml[pl][kr*28]; \
      int e1 = aofs[kr+1]; \
      for(int e=aofs[kr]; e<e1; e++){ \
        int meta = attij[e]; \
        Mrow[meta & 31] += attw[e] * sh_s[pl][(meta>>5) & 15]; \
      } \
    } \
    __syncthreads(); \
  } while(0)

// ---------------- attention scores: s = <q[dst], couple(k[src],Bf)>/20 ----------------
__global__ __launch_bounds__(128) void k_s(const int* nbr, const float* Wb, float* ws){
  __shared__ __align__(16) float Ml[8][25*28];
  __shared__ float sh_s[8][9];
  int tid = threadIdx.x, pl = tid >> 4, g = tid & 15;
  int p = blockIdx.x*8 + pl;
  M_BUILD();
  int dst = nbr[2*p], src = nbr[2*p+1];
  float q_r[25], xk_r[25];
  #pragma unroll
  for(int i=0;i<25;i++){
    q_r[i]  = ws[WS_XQ + dst*400 + i*16 + g];
    xk_r[i] = ws[WS_XK + src*400 + i*16 + g];
  }
  float wbf = 0.f;
  #pragma unroll
  for(int k=0;k<16;k++) wbf += ws[WS_RB + p*16 + k] * Wb[k*16+g];
  float sacc = 0.f;
  #pragma unroll
  for(int k=0;k<25;k++){
    const float* Mr = &Ml[pl][k*28];
    float kf = 0.f;
    #pragma unroll
    for(int c=0;c<6;c++){
      float4 m4 = *(const float4*)(Mr + 4*c);
      kf += m4.x*xk_r[4*c] + m4.y*xk_r[4*c+1] + m4.z*xk_r[4*c+2] + m4.w*xk_r[4*c+3];
    }
    kf += Mr[24]*xk_r[24];
    sacc += q_r[k]*kf;
  }
  float sl = wbf * sacc;
  #pragma unroll
  for(int off=1; off<16; off<<=1) sl += __shfl_xor(sl, off, 16);
  if(g == 0){
    float sv = scrub(sl * 0.05f);        // / sqrt(25*16)
    ws[WS_S + p] = sv;
    atomicMax((unsigned*)ws + WS_M + dst, fenc(sv));
  }
}

// ---------------- exp + denominator ----------------
__global__ void k_e(const int* nbr, float* ws){
  int p = blockIdx.x*256 + threadIdx.x;
  if(p >= NP) return;
  int dst = nbr[2*p];
  float m = fdec(((const unsigned*)ws)[WS_M + dst]);
  float e = expf(fminf(ws[WS_S + p] - m, 0.f));   // s-m <= 0 by construction
  ws[WS_E + p] = e;
  unsafeAtomicAdd(ws + WS_DEN + dst, e);
}

// ---------------- aggregation: agg[dst] += alpha * couple(v[src],Bf) ----------------
__global__ __launch_bounds__(128) void k_agg(const int* nbr, const float* Wb, float* ws){
  __shared__ __align__(16) float Ml[8][25*28];
  __shared__ float sh_s[8][9];
  int tid = threadIdx.x, pl = tid >> 4, g = tid & 15;
  int p = blockIdx.x*8 + pl;
  M_BUILD();
  int dst = nbr[2*p], src = nbr[2*p+1];
  float xv_r[25];
  #pragma unroll
  for(int i=0;i<25;i++) xv_r[i] = ws[WS_XV + src*400 + i*16 + g];
  float wbf = 0.f;
  #pragma unroll
  for(int k=0;k<16;k++) wbf += ws[WS_RB + p*16 + k] * Wb[k*16+g];
  float alpha = ws[WS_E + p] / (ws[WS_DEN + dst] + 1e-9f);
  float aw = alpha * wbf;
  #pragma unroll
  for(int k=0;k<25;k++){
    const float* Mr = &Ml[pl][k*28];
    float vf = 0.f;
    #pragma unroll
    for(int c=0;c<6;c++){
      float4 m4 = *(const float4*)(Mr + 4*c);
      vf += m4.x*xv_r[4*c] + m4.y*xv_r[4*c+1] + m4.z*xv_r[4*c+2] + m4.w*xv_r[4*c+3];
    }
    vf += Mr[24]*xv_r[24];
    unsafeAtomicAdd(&ws[WS_AGG + dst*400 + k*16 + g], scrub(aw*vf));
  }
}

// ---------------- output pdense + bias ----------------
__global__ __launch_bounds__(256) void k_o(const float* Wo, const float* bo, float* ws){
  int tid = threadIdx.x, al = tid >> 4, g = tid & 15;
  int a = blockIdx.x*16 + al;
  const float* agg = ws + WS_AGG + a*400;
  int i = 0;
  #pragma unroll
  for(int l=0;l<5;l++){
    float wo[16];
    #pragma unroll
    for(int f2=0;f2<16;f2++) wo[f2] = Wo[(l*16+f2)*16+g];
    for(int mi=0; mi<2*l+1; mi++, i++){
      float acc = 0.f;
      #pragma unroll
      for(int f2=0;f2<16;f2++) acc += agg[i*16+f2]*wo[f2];
      if(i == 0) acc += bo[g];
      ws[WS_X + a*400 + i*16 + g] = scrub(acc);
    }
  }
}

// ---------------- embedding residual + f32 output ----------------
__global__ void k_resout(const int* aZ, const float* emb, const float* Wemb,
                         const float* bemb, const float* ws, float* out){
  int idx = blockIdx.x*256 + threadIdx.x;
  if(idx >= NA*400) return;
  int a = idx/400, r2 = idx%400, i = r2>>4, f = r2&15;
  float v = ws[WS_X + idx];
  if(i == 0){
    int Z = aZ[a];
    float res = bemb[f];
    #pragma unroll
    for(int e2=0;e2<32;e2++) res += emb[Z*32+e2] * Wemb[e2*16+f];
    v += res;
  }
  out[idx] = scrub(v);
}

extern "C" void kernel_launch(void* const* d_in, const int* in_sizes, int n_in,
                              void* d_out, int out_size, void* d_ws, size_t ws_size,
                              hipStream_t stream){
  (void)in_sizes; (void)n_in; (void)out_size;
  if(ws_size < (size_t)WS_END * sizeof(float)) return;
  float* ws = (float*)d_ws;
  const int* aZ  = (const int*)d_in[0];
  const int* nbr = (const int*)d_in[1];
  const float* disp = (const float*)d_in[2];
  const float* Wrad = (const float*)d_in[3];
  const float* emb  = (const float*)d_in[4];
  const float* Wemb = (const float*)d_in[5];
  const float* bemb = (const float*)d_in[6];
  const float* W1   = (const float*)d_in[7];
  const float* W2   = (const float*)d_in[8];
  const float* W3   = (const float*)d_in[9];

  hipMemsetAsync(ws + WS_SUMS, 0, NA*144*sizeof(float), stream);
  hipMemsetAsync(ws + WS_CNT,  0, NA*sizeof(float), stream);
  kq_Y<<<2,256,0,stream>>>(ws);
  kq_G<<<22,256,0,stream>>>(ws);
  kq_lists<<<1,64,0,stream>>>(ws);
  k_pair<<<192,256,0,stream>>>(disp, ws);
  k_td<<<3072,256,0,stream>>>(aZ, nbr, Wrad, W1, W2, W3, ws);
  k_x<<<6400,256,0,stream>>>(ws);

  for(int l=0;l<2;l++){
    const float* Wb = (const float*)d_in[10+6*l];
    const float* Wq = (const float*)d_in[11+6*l];
    const float* Wk = (const float*)d_in[12+6*l];
    const float* Wv = (const float*)d_in[13+6*l];
    const float* Wo = (const float*)d_in[14+6*l];
    const float* bo = (const float*)d_in[15+6*l];
    k_qkv<<<256,256,0,stream>>>(Wq, Wk, Wv, ws);
    k_initm<<<16,256,0,stream>>>(ws);
    hipMemsetAsync(ws + WS_AGG, 0, NA*400*sizeof(float), stream);
    k_s<<<6144,128,0,stream>>>(nbr, Wb, ws);
    k_e<<<192,256,0,stream>>>(nbr, ws);
    k_agg<<<6144,128,0,stream>>>(nbr, Wb, ws);
    k_o<<<256,256,0,stream>>>(Wo, bo, ws);
  }
  k_resout<<<6400,256,0,stream>>>(aZ, emb, Wemb, bemb, ws, (float*)d_out);
}